// Round 28
// baseline (540.511 us; speedup 1.0000x reference)
//
#include <hip/hip_runtime.h>
#include <hip/hip_bf16.h>

// SpatialTransformer on MI355X. Round 28: r27 (passed 532.9us) + the LAST
// exonerated change, T14 async-stage prefetch in attention: K/V of tile t+1
// load into REGISTERS during compute(t); regs->LDS writes stay in the same
// barrier interval. Always-write semantics preserved (regs zeroed for masked
// kv). r16's marginal failure is attributed to the half-K bug. Math is
// load-motion only => absmax must remain bit-exact 0.03125.

#define HD 8
#define DHD 80
#define CCH 640
#define SQ 1024

using short8  = __attribute__((ext_vector_type(8))) short;
using floatx4 = __attribute__((ext_vector_type(4))) float;

__device__ __forceinline__ float bf2f(ushort u) {
  union { unsigned int i; float f; } v; v.i = ((unsigned int)u) << 16; return v.f;
}
__device__ __forceinline__ ushort f2bf(float f) {
  union { float f; unsigned int i; } v; v.f = f;
  unsigned int r = v.i + 0x7FFFu + ((v.i >> 16) & 1u);
  return (ushort)(r >> 16);
}
// 0.5*g*(1+tanh(z)) == g/(1+exp(-2z)), z = 0.79788456*g*(1+0.044715*g^2)
__device__ __forceinline__ float gelu_gate(float g) {
  float z = 0.7978845608f * g * (1.0f + 0.044715f * g * g);
  return g / (1.0f + __expf(-2.0f * z));
}

typedef const __attribute__((address_space(1))) void* gas_ptr;
typedef __attribute__((address_space(3))) void* las_ptr;
__device__ __forceinline__ void gload_lds16(const void* g, void* l) {
  __builtin_amdgcn_global_load_lds((gas_ptr)g, (las_ptr)l, 16, 0, 0);
}

// ---------------------------------------------------------------- GEMM
// C[M,N] = A[M,K]@BT[N,K]^T (+bias)(+res). BM=128, BN in {128,64}, BK=32,
// 4 waves 2x2. 2-buffer LDS, __syncthreads-delimited K-loop.
// outF and outB may BOTH be set (dual-write: fp32 + bf16 of the same value).
template<int BN>
__global__ __launch_bounds__(256) void gemm_bf16_kernel(
    const ushort* __restrict__ A, const ushort* __restrict__ BT,
    const float* __restrict__ bias, const float* __restrict__ res,
    float* __restrict__ outF, ushort* __restrict__ outB,
    int M, int N, int K, int nby, int q8, int r8)
{
  constexpr int NT = BN / 32;
  __shared__ ushort As[2][128][32];
  __shared__ ushort Bs[2][BN][32];
  const int tid  = threadIdx.x;
  const int lane = tid & 63;
  const int wave = tid >> 6;
  const int wm = (wave >> 1) * 64, wn = (wave & 1) * (BN / 2);

  // XCD-chunked bijective swizzle (bn-fastest logical order).
  const int orig = blockIdx.x;
  const int xcd = orig & 7, bix = orig >> 3;
  const int logical = (xcd < r8) ? xcd * (q8 + 1) + bix
                                 : r8 * (q8 + 1) + (xcd - r8) * q8 + bix;
  const int bm = (logical / nby) * 128;
  const int bn = (logical % nby) * BN;

  const int fr = lane & 15, fk = (lane >> 4) * 8;
  const bool full = (bm + 128 <= M);
  const int nt = K >> 5;

  floatx4 acc[4][NT];
  #pragma unroll
  for (int i = 0; i < 4; ++i)
    #pragma unroll
    for (int j = 0; j < NT; ++j) acc[i][j] = (floatx4){0.f, 0.f, 0.f, 0.f};

  const int lr = lane >> 2, lc = (lane & 3) * 8;
  const ushort* pA0 = A  + (size_t)(bm + wave * 16 + lr) * K + lc;
  const ushort* pA1 = pA0 + (size_t)64 * K;
  const ushort* pB0 = BT + (size_t)(bn + wave * 16 + lr) * K + lc;
  const ushort* pB1 = pB0 + (size_t)64 * K;
  const int r0 = tid >> 2, c0 = (tid & 3) * 8;

  auto stage = [&](int nb, int t) {
    const int kt = t * 32;
    if (full) {
      gload_lds16(pA0 + kt, &As[nb][wave * 16][0]);
      gload_lds16(pA1 + kt, &As[nb][wave * 16 + 64][0]);
      gload_lds16(pB0 + kt, &Bs[nb][wave * 16][0]);
      if (BN == 128) gload_lds16(pB1 + kt, &Bs[nb][wave * 16 + 64][0]);
    } else {
      #pragma unroll
      for (int it = 0; it < 2; ++it) {
        int r = r0 + it * 64;
        int gm = bm + r;
        uint4 va = make_uint4(0u, 0u, 0u, 0u);
        if (gm < M) va = *(const uint4*)(A + (size_t)gm * K + kt + c0);
        *(uint4*)(&As[nb][r][c0]) = va;
        if (r < BN) {
          int gn = bn + r;
          uint4 vb = make_uint4(0u, 0u, 0u, 0u);
          if (gn < N) vb = *(const uint4*)(BT + (size_t)gn * K + kt + c0);
          *(uint4*)(&Bs[nb][r][c0]) = vb;
        }
      }
    }
  };

  stage(0, 0);
  __syncthreads();
  int cur = 0;
  for (int t = 0; t < nt; ++t) {
    if (t + 1 < nt) stage(cur ^ 1, t + 1);
    short8 af[4], bfr[NT];
    #pragma unroll
    for (int mi = 0; mi < 4; ++mi) af[mi]  = *(const short8*)(&As[cur][wm + mi * 16 + fr][fk]);
    #pragma unroll
    for (int ni = 0; ni < NT; ++ni) bfr[ni] = *(const short8*)(&Bs[cur][wn + ni * 16 + fr][fk]);
    #pragma unroll
    for (int mi = 0; mi < 4; ++mi)
      #pragma unroll
      for (int ni = 0; ni < NT; ++ni)
        acc[mi][ni] = __builtin_amdgcn_mfma_f32_16x16x32_bf16(af[mi], bfr[ni], acc[mi][ni], 0, 0, 0);
    __syncthreads();
    cur ^= 1;
  }

  const int fq = (lane >> 4) * 4;
  #pragma unroll
  for (int mi = 0; mi < 4; ++mi)
    #pragma unroll
    for (int rr = 0; rr < 4; ++rr) {
      int gm = bm + wm + mi * 16 + fq + rr;
      if (gm >= M) continue;
      #pragma unroll
      for (int ni = 0; ni < NT; ++ni) {
        int col = bn + wn + ni * 16 + fr;
        float v = acc[mi][ni][rr];
        if (bias) v += bias[col];
        if (res) v += res[(size_t)gm * N + col];
        size_t o = (size_t)gm * N + col;
        if (outF) outF[o] = v;
        if (outB) outB[o] = f2bf(v);
      }
    }
}

// Fused GEGLU: out = (A@Bx^T + bx) * gelu(A@Bg^T + bg). BM=128, BN=64/op.
__global__ __launch_bounds__(256) void gemm_geglu_kernel(
    const ushort* __restrict__ A, const ushort* __restrict__ BTx,
    const ushort* __restrict__ BTg, const float* __restrict__ bx,
    const float* __restrict__ bg, ushort* __restrict__ outB,
    int M, int N, int K, int nby, int q8, int r8)
{
  __shared__ ushort As[2][128][32];
  __shared__ ushort Bsx[2][64][32];
  __shared__ ushort Bsg[2][64][32];
  const int tid  = threadIdx.x;
  const int lane = tid & 63;
  const int wave = tid >> 6;
  const int wm = (wave >> 1) * 64, wn = (wave & 1) * 32;

  const int orig = blockIdx.x;
  const int xcd = orig & 7, bix = orig >> 3;
  const int logical = (xcd < r8) ? xcd * (q8 + 1) + bix
                                 : r8 * (q8 + 1) + (xcd - r8) * q8 + bix;
  const int bm = (logical / nby) * 128;
  const int bn = (logical % nby) * 64;

  const int fr = lane & 15, fk = (lane >> 4) * 8;
  const int nt = K >> 5;

  floatx4 accx[4][2], accg[4][2];
  #pragma unroll
  for (int i = 0; i < 4; ++i)
    #pragma unroll
    for (int j = 0; j < 2; ++j) {
      accx[i][j] = (floatx4){0.f, 0.f, 0.f, 0.f};
      accg[i][j] = (floatx4){0.f, 0.f, 0.f, 0.f};
    }

  const int lr = lane >> 2, lc = (lane & 3) * 8;
  const ushort* pA0 = A   + (size_t)(bm + wave * 16 + lr) * K + lc;
  const ushort* pA1 = pA0 + (size_t)64 * K;
  const ushort* pBx = BTx + (size_t)(bn + wave * 16 + lr) * K + lc;
  const ushort* pBg = BTg + (size_t)(bn + wave * 16 + lr) * K + lc;

  auto stage = [&](int nb, int t) {
    const int kt = t * 32;
    gload_lds16(pA0 + kt, &As[nb][wave * 16][0]);
    gload_lds16(pA1 + kt, &As[nb][wave * 16 + 64][0]);
    gload_lds16(pBx + kt, &Bsx[nb][wave * 16][0]);
    gload_lds16(pBg + kt, &Bsg[nb][wave * 16][0]);
  };

  stage(0, 0);
  __syncthreads();
  int cur = 0;
  for (int t = 0; t < nt; ++t) {
    if (t + 1 < nt) stage(cur ^ 1, t + 1);
    short8 af[4], bfx[2], bfg[2];
    #pragma unroll
    for (int mi = 0; mi < 4; ++mi) af[mi] = *(const short8*)(&As[cur][wm + mi * 16 + fr][fk]);
    #pragma unroll
    for (int ni = 0; ni < 2; ++ni) {
      bfx[ni] = *(const short8*)(&Bsx[cur][wn + ni * 16 + fr][fk]);
      bfg[ni] = *(const short8*)(&Bsg[cur][wn + ni * 16 + fr][fk]);
    }
    #pragma unroll
    for (int mi = 0; mi < 4; ++mi)
      #pragma unroll
      for (int ni = 0; ni < 2; ++ni) {
        accx[mi][ni] = __builtin_amdgcn_mfma_f32_16x16x32_bf16(af[mi], bfx[ni], accx[mi][ni], 0, 0, 0);
        accg[mi][ni] = __builtin_amdgcn_mfma_f32_16x16x32_bf16(af[mi], bfg[ni], accg[mi][ni], 0, 0, 0);
      }
    __syncthreads();
    cur ^= 1;
  }

  const int fq = (lane >> 4) * 4;
  #pragma unroll
  for (int mi = 0; mi < 4; ++mi)
    #pragma unroll
    for (int rr = 0; rr < 4; ++rr) {
      int gm = bm + wm + mi * 16 + fq + rr;
      #pragma unroll
      for (int ni = 0; ni < 2; ++ni) {
        int col = bn + wn + ni * 16 + fr;
        float xx = accx[mi][ni][rr] + bx[col];
        float g  = accg[mi][ni][rr] + bg[col];
        outB[(size_t)gm * N + col] = f2bf(xx * gelu_gate(g));
      }
    }
}

// ---------------------------------------------------------------- attention
// MFMA flash attention: 8 waves x 16 q-rows = 128 q/block, KVB=64, grid 512,
// XCD-cluster swizzle, setprio. T14: K/V of tile t+1 prefetched to REGISTERS
// during compute(t); regs->LDS writes in the same barrier interval. Always
// writes (zeros for masked kv). Full-K staging (640 chunks).
#define KVB 64

__global__ __launch_bounds__(512) void attn_mfma_kernel(
    const ushort* __restrict__ Qp, int rsq,
    const ushort* __restrict__ Kp, const ushort* __restrict__ Vp, int rskv,
    ushort* __restrict__ O, int Sq, int Sk)
{
  __shared__ ushort Ks[KVB][104];   // kv x d (d 0..95, 80..95 zeroed; +8 pad)
  __shared__ ushort Vt[80][88];     // d x kv
  __shared__ ushort Ps[8][16][88];  // per-wave P tile
  const int tid  = threadIdx.x;
  const int lane = tid & 63;
  const int w    = tid >> 6;        // 0..7
  const int l15  = lane & 15;
  const int lg   = lane >> 4;
  const int nqt  = Sq >> 7;         // q-tiles of 128
  // XCD-clustering swizzle: all nqt q-tiles of one bh share an XCD's L2.
  const int xcd8 = blockIdx.x & 7;
  const int sblk = blockIdx.x >> 3;
  const int qt   = sblk % nqt;
  const int bh   = (sblk / nqt) * 8 + xcd8;
  const int h    = bh & (HD - 1);
  const int b    = bh / HD;
  const int q0   = qt * 128 + w * 16;

  short8 qf[3];
  #pragma unroll
  for (int kc = 0; kc < 3; ++kc) {
    int d0 = kc * 32 + lg * 8;
    if (d0 < DHD)
      qf[kc] = *(const short8*)(Qp + (size_t)(b * Sq + q0 + l15) * rsq + h * DHD + d0);
    else
      qf[kc] = (short8){0, 0, 0, 0, 0, 0, 0, 0};
  }

  floatx4 oa[5];
  #pragma unroll
  for (int nt = 0; nt < 5; ++nt) oa[nt] = (floatx4){0.f, 0.f, 0.f, 0.f};
  float m[4], lsum[4];
  #pragma unroll
  for (int r = 0; r < 4; ++r) { m[r] = -1e30f; lsum[r] = 0.f; }

  for (int c = tid; c < 128; c += 512)
    *(uint4*)(&Ks[c >> 1][80 + (c & 1) * 8]) = make_uint4(0u, 0u, 0u, 0u);

  // staging index maps (constant per thread)
  const int kr0 = tid / 10, ks0 = tid % 10;                 // K chunk A (tid < 640 always)
  const int kr1 = (tid + 512) / 10, ks1 = (tid + 512) % 10; // K chunk B (tid < 128)
  const bool k2ok = (tid < 128);
  const int vkv = tid & 63, vdblk0 = tid >> 6;              // V ladder

  const ushort* Kbase = Kp + (size_t)b * Sk * rskv + h * DHD;
  const ushort* Vbase = Vp + (size_t)b * Sk * rskv + h * DHD + vdblk0 * 8;

  uint4  kreg0, kreg1;
  short8 vreg[3];

  auto prefetch = [&](int kt) {
    int kg0 = kt + kr0;
    kreg0 = (kg0 < Sk) ? *(const uint4*)(Kbase + (size_t)kg0 * rskv + ks0 * 8)
                       : make_uint4(0u, 0u, 0u, 0u);
    if (k2ok) {
      int kg1 = kt + kr1;
      kreg1 = (kg1 < Sk) ? *(const uint4*)(Kbase + (size_t)kg1 * rskv + ks1 * 8)
                         : make_uint4(0u, 0u, 0u, 0u);
    }
    int kvg = kt + vkv;
    const bool ok = (kvg < Sk);
    #pragma unroll
    for (int it = 0; it < 3; ++it) {
      if (vdblk0 + it * 4 < 10) {
        vreg[it] = (short8){0, 0, 0, 0, 0, 0, 0, 0};
        if (ok) vreg[it] = *(const short8*)(Vbase + (size_t)kvg * rskv + it * 32);
      }
    }
  };

  prefetch(0);

  for (int kt = 0; kt < Sk; kt += KVB) {
    __syncthreads();                       // bar_A: prior compute done with LDS
    // write prefetched K tile (same addresses as r27's staging)
    *(uint4*)(&Ks[kr0][ks0 * 8]) = kreg0;
    if (k2ok) *(uint4*)(&Ks[kr1][ks1 * 8]) = kreg1;
    // write prefetched V tile (always writes; zeros for masked kv)
    {
      ushort* dst = &Vt[vdblk0 * 8][vkv];
      #pragma unroll
      for (int it = 0; it < 3; ++it) {
        if (vdblk0 + it * 4 < 10) {
          #pragma unroll
          for (int e = 0; e < 8; ++e)
            dst[(it * 32 + e) * 88] = (ushort)vreg[it][e];
        }
      }
    }
    __syncthreads();                       // bar_B: tile published
    if (kt + KVB < Sk) prefetch(kt + KVB); // loads hide under compute below

    short8 kf[4][3];
    #pragma unroll
    for (int nt = 0; nt < 4; ++nt)
      #pragma unroll
      for (int kc = 0; kc < 3; ++kc)
        kf[nt][kc] = *(const short8*)(&Ks[nt * 16 + l15][kc * 32 + lg * 8]);
    floatx4 s[4];
    #pragma unroll
    for (int nt = 0; nt < 4; ++nt) s[nt] = (floatx4){0.f, 0.f, 0.f, 0.f};
    __builtin_amdgcn_s_setprio(1);
    #pragma unroll
    for (int nt = 0; nt < 4; ++nt)
      #pragma unroll
      for (int kc = 0; kc < 3; ++kc)
        s[nt] = __builtin_amdgcn_mfma_f32_16x16x32_bf16(qf[kc], kf[nt][kc], s[nt], 0, 0, 0);
    __builtin_amdgcn_s_setprio(0);

    const bool masked = (kt + KVB > Sk);
    #pragma unroll
    for (int r = 0; r < 4; ++r) {
      float sv[4];
      #pragma unroll
      for (int nt = 0; nt < 4; ++nt) {
        float t = s[nt][r];
        sv[nt] = (masked && (kt + nt * 16 + l15 >= Sk)) ? -1e30f : t;
      }
      float mx = fmaxf(fmaxf(sv[0], sv[1]), fmaxf(sv[2], sv[3]));
      mx = fmaxf(mx, __shfl_xor(mx, 1));
      mx = fmaxf(mx, __shfl_xor(mx, 2));
      mx = fmaxf(mx, __shfl_xor(mx, 4));
      mx = fmaxf(mx, __shfl_xor(mx, 8));
      float mn = fmaxf(m[r], mx);
      float al = __expf(m[r] - mn);
      m[r] = mn;
      float lt = 0.f;
      #pragma unroll
      for (int nt = 0; nt < 4; ++nt) {
        float p = __expf(sv[nt] - mn);
        lt += p;
        Ps[w][lg * 4 + r][nt * 16 + l15] = f2bf(p);
      }
      lt += __shfl_xor(lt, 1);
      lt += __shfl_xor(lt, 2);
      lt += __shfl_xor(lt, 4);
      lt += __shfl_xor(lt, 8);
      lsum[r] = lsum[r] * al + lt;
      #pragma unroll
      for (int nt = 0; nt < 5; ++nt) oa[nt][r] *= al;
    }

    short8 pf[2];
    #pragma unroll
    for (int kc2 = 0; kc2 < 2; ++kc2)
      pf[kc2] = *(const short8*)(&Ps[w][l15][kc2 * 32 + lg * 8]);
    __builtin_amdgcn_s_setprio(1);
    #pragma unroll
    for (int kc2 = 0; kc2 < 2; ++kc2)
      #pragma unroll
      for (int nt = 0; nt < 5; ++nt) {
        short8 vf = *(const short8*)(&Vt[nt * 16 + l15][kc2 * 32 + lg * 8]);
        oa[nt] = __builtin_amdgcn_mfma_f32_16x16x32_bf16(pf[kc2], vf, oa[nt], 0, 0, 0);
      }
    __builtin_amdgcn_s_setprio(0);
  }

  #pragma unroll
  for (int r = 0; r < 4; ++r) {
    float inv = 1.f / lsum[r];
    size_t row = (size_t)(b * Sq + q0 + lg * 4 + r) * CCH + h * DHD;
    #pragma unroll
    for (int nt = 0; nt < 5; ++nt)
      O[row + nt * 16 + l15] = f2bf(oa[nt][r] * inv);
  }
}

// ---------------------------------------------------------------- norms
__global__ __launch_bounds__(256) void layernorm_kernel(
    const float* __restrict__ X, const float* __restrict__ g,
    const float* __restrict__ bt, ushort* __restrict__ out)
{
  int row  = blockIdx.x * 4 + (threadIdx.x >> 6);
  int lane = threadIdx.x & 63;
  const float* xr = X + (size_t)row * CCH;
  float v[10];
  float s = 0.f, ss = 0.f;
  #pragma unroll
  for (int i = 0; i < 10; ++i) {
    float x = xr[lane + i * 64];
    v[i] = x; s += x; ss += x * x;
  }
  #pragma unroll
  for (int msk = 1; msk < 64; msk <<= 1) { s += __shfl_xor(s, msk); ss += __shfl_xor(ss, msk); }
  float mean = s * (1.f / 640.f);
  float var  = ss * (1.f / 640.f) - mean * mean;
  float rs   = rsqrtf(var + 1e-5f);
  ushort* orow = out + (size_t)row * CCH;
  #pragma unroll
  for (int i = 0; i < 10; ++i) {
    int c = lane + i * 64;
    orow[c] = f2bf((v[i] - mean) * rs * g[c] + bt[c]);
  }
}

__global__ __launch_bounds__(256) void groupnorm_kernel(
    const float* __restrict__ X, const float* __restrict__ gamma,
    const float* __restrict__ beta, ushort* __restrict__ out)
{
  int b = blockIdx.x >> 5;
  int g = blockIdx.x & 31;
  int tid = threadIdx.x;
  const float* base = X + (size_t)b * SQ * CCH + g * 20;
  float s = 0.f, ss = 0.f;
  for (int p = tid; p < SQ; p += 256) {
    const float* rp = base + (size_t)p * CCH;
    #pragma unroll
    for (int c = 0; c < 20; ++c) { float x = rp[c]; s += x; ss += x * x; }
  }
  #pragma unroll
  for (int msk = 1; msk < 64; msk <<= 1) { s += __shfl_xor(s, msk); ss += __shfl_xor(ss, msk); }
  __shared__ float red[2][4];
  int lane = tid & 63, wv = tid >> 6;
  if (lane == 0) { red[0][wv] = s; red[1][wv] = ss; }
  __syncthreads();
  s  = red[0][0] + red[0][1] + red[0][2] + red[0][3];
  ss = red[1][0] + red[1][1] + red[1][2] + red[1][3];
  float mean = s * (1.f / 20480.f);
  float var  = ss * (1.f / 20480.f) - mean * mean;
  float rstd = rsqrtf(var + 1e-5f);
  ushort* ob = out + (size_t)b * SQ * CCH + g * 20;
  for (int p = tid; p < SQ; p += 256) {
    const float* rp = base + (size_t)p * CCH;
    ushort* op = ob + (size_t)p * CCH;
    #pragma unroll
    for (int c = 0; c < 20; ++c)
      op[c] = f2bf((rp[c] - mean) * rstd * gamma[g * 20 + c] + beta[g * 20 + c]);
  }
}

// ---------------------------------------------------------------- prep
__global__ __launch_bounds__(256) void transpose_cast_kernel(
    const float* __restrict__ W, ushort* __restrict__ WT, int K, int ld,
    int coff, float scale)
{
  __shared__ float tile[32][33];
  const int tx = threadIdx.x, ty = threadIdx.y;
  const int k0 = blockIdx.x * 32, n0 = blockIdx.y * 32;
  #pragma unroll
  for (int i = 0; i < 4; ++i)
    tile[ty + i * 8][tx] = W[(size_t)(k0 + ty + i * 8) * ld + coff + n0 + tx];
  __syncthreads();
  #pragma unroll
  for (int i = 0; i < 4; ++i)
    WT[(size_t)(n0 + ty + i * 8) * K + k0 + tx] = f2bf(tile[tx][ty + i * 8] * scale);
}

__global__ void cast_kernel(const float* __restrict__ X, ushort* __restrict__ Y, int n)
{
  int i = (blockIdx.x * 256 + threadIdx.x) * 4;
  if (i < n) {
    float4 v = *(const float4*)(X + i);
    ushort4 o;
    o.x = f2bf(v.x); o.y = f2bf(v.y); o.z = f2bf(v.z); o.w = f2bf(v.w);
    *(ushort4*)(Y + i) = o;
  }
}

// ---------------------------------------------------------------- host
static inline void gemm(hipStream_t st, const ushort* A, const ushort* BT,
                        const float* bias, const float* res,
                        float* outF, ushort* outB, int M, int N, int K)
{
  int nbx = (M + 127) / 128;
  if (N % 128 == 0 && N > 640 && nbx * (N / 128) >= 512) {
    int nby = N / 128, nwg = nbx * nby;
    gemm_bf16_kernel<128><<<dim3(nwg), dim3(256), 0, st>>>(
        A, BT, bias, res, outF, outB, M, N, K, nby, nwg / 8, nwg % 8);
  } else {
    int nby = N / 64, nwg = nbx * nby;
    gemm_bf16_kernel<64><<<dim3(nwg), dim3(256), 0, st>>>(
        A, BT, bias, res, outF, outB, M, N, K, nby, nwg / 8, nwg % 8);
  }
}

extern "C" void kernel_launch(void* const* d_in, const int* in_sizes, int n_in,
                              void* d_out, int out_size, void* d_ws, size_t ws_size,
                              hipStream_t stream)
{
  const float* inputs  = (const float*)d_in[0];
  const float* context = (const float*)d_in[1];
  const float* gn_g    = (const float*)d_in[2];
  const float* gn_b    = (const float*)d_in[3];
  const float* w_proj1 = (const float*)d_in[4];
  const float* b_proj1 = (const float*)d_in[5];
  const float* ln1_g   = (const float*)d_in[6];
  const float* ln1_b   = (const float*)d_in[7];
  const float* wq1     = (const float*)d_in[8];
  const float* wk1     = (const float*)d_in[9];
  const float* wv1     = (const float*)d_in[10];
  const float* wo1     = (const float*)d_in[11];
  const float* bo1     = (const float*)d_in[12];
  const float* ln2_g   = (const float*)d_in[13];
  const float* ln2_b   = (const float*)d_in[14];
  const float* wq2     = (const float*)d_in[15];
  const float* wk2     = (const float*)d_in[16];
  const float* wv2     = (const float*)d_in[17];
  const float* wo2     = (const float*)d_in[18];
  const float* bo2     = (const float*)d_in[19];
  const float* ln3_g   = (const float*)d_in[20];
  const float* ln3_b   = (const float*)d_in[21];
  const float* w_geglu = (const float*)d_in[22];
  const float* b_geglu = (const float*)d_in[23];
  const float* w_ffout = (const float*)d_in[24];
  const float* b_ffout = (const float*)d_in[25];
  const float* w_proj2 = (const float*)d_in[26];
  const float* b_proj2 = (const float*)d_in[27];

  const float qscale = 0.11180339887498949f;  // 80^-0.5, folded into wq

  char* p = (char*)d_ws;
  auto alloc = [&](size_t bytes) -> char* {
    char* r = p; p += (bytes + 255) & ~(size_t)255; return r;
  };
  ushort* wT_p1   = (ushort*)alloc(640 * 640 * 2);
  ushort* wT_qkv1 = (ushort*)alloc((size_t)1920 * 640 * 2);
  ushort* wT_o1   = (ushort*)alloc(640 * 640 * 2);
  ushort* wT_q2   = (ushort*)alloc(640 * 640 * 2);
  ushort* wT_kv2  = (ushort*)alloc((size_t)1280 * 768 * 2);
  ushort* wT_o2   = (ushort*)alloc(640 * 640 * 2);
  ushort* wT_gx   = (ushort*)alloc((size_t)2560 * 640 * 2);
  ushort* wT_gg   = (ushort*)alloc((size_t)2560 * 640 * 2);
  ushort* wT_ff   = (ushort*)alloc((size_t)640 * 2560 * 2);
  ushort* wT_p2   = (ushort*)alloc(640 * 640 * 2);
  ushort* ctxb    = (ushort*)alloc((size_t)616 * 768 * 2);
  float*  x       = (float*)alloc((size_t)8192 * 640 * 4);
  ushort* lnb     = (ushort*)alloc((size_t)8192 * 640 * 2);
  ushort* R       = (ushort*)alloc((size_t)8192 * 2560 * 2);  // qkv / cross-q / hb
  ushort* kvb     = (ushort*)alloc((size_t)616 * 1280 * 2);
  ushort* qkvb = R;      // self q/k/v [8192][1920]
  ushort* qbx  = R;      // cross q [8192][640]
  ushort* hb   = R;      // GEGLU out [8192][2560]
  ushort* ab   = lnb;    // attn out aliases lnb

  auto T = [&](const float* W, ushort* WT, int K, int Nout, int ld, int coff, float sc) {
    dim3 g(K / 32, Nout / 32);
    transpose_cast_kernel<<<g, dim3(32, 8), 0, stream>>>(W, WT, K, ld, coff, sc);
  };
  T(w_proj1, wT_p1, 640, 640, 640, 0, 1.f);
  T(wq1, wT_qkv1,              640, 640, 640, 0, qscale);
  T(wk1, wT_qkv1 + 640 * 640,  640, 640, 640, 0, 1.f);
  T(wv1, wT_qkv1 + 1280 * 640, 640, 640, 640, 0, 1.f);
  T(wo1, wT_o1, 640, 640, 640, 0, 1.f);
  T(wq2, wT_q2, 640, 640, 640, 0, qscale);
  T(wk2, wT_kv2,             768, 640, 640, 0, 1.f);
  T(wv2, wT_kv2 + 640 * 768, 768, 640, 640, 0, 1.f);
  T(wo2, wT_o2, 640, 640, 640, 0, 1.f);
  T(w_geglu, wT_gx, 640, 2560, 5120, 0, 1.f);
  T(w_geglu, wT_gg, 640, 2560, 5120, 2560, 1.f);
  T(w_ffout, wT_ff, 2560, 640, 640, 0, 1.f);
  T(w_proj2, wT_p2, 640, 640, 640, 0, 1.f);
  cast_kernel<<<dim3((616 * 768 / 4 + 255) / 256), dim3(256), 0, stream>>>(context, ctxb, 616 * 768);

  // GN -> proj1
  groupnorm_kernel<<<dim3(256), dim3(256), 0, stream>>>(inputs, gn_g, gn_b, lnb);
  gemm(stream, lnb, wT_p1, b_proj1, nullptr, x, nullptr, 8192, 640, 640);

  // self-attention
  layernorm_kernel<<<dim3(2048), dim3(256), 0, stream>>>(x, ln1_g, ln1_b, lnb);
  gemm(stream, lnb, wT_qkv1, nullptr, nullptr, nullptr, qkvb, 8192, 1920, 640);
  attn_mfma_kernel<<<dim3(512), dim3(512), 0, stream>>>(qkvb, 1920, qkvb + 640, qkvb + 1280, 1920, ab, 1024, 1024);
  gemm(stream, ab, wT_o1, bo1, x, x, nullptr, 8192, 640, 640);

  // cross-attention
  layernorm_kernel<<<dim3(2048), dim3(256), 0, stream>>>(x, ln2_g, ln2_b, lnb);
  gemm(stream, lnb, wT_q2, nullptr, nullptr, nullptr, qbx, 8192, 640, 640);
  gemm(stream, ctxb, wT_kv2, nullptr, nullptr, nullptr, kvb, 616, 1280, 768);
  attn_mfma_kernel<<<dim3(512), dim3(512), 0, stream>>>(qbx, 640, kvb, kvb + 640, 1280, ab, 1024, 77);
  gemm(stream, ab, wT_o2, bo2, x, x, nullptr, 8192, 640, 640);

  // GEGLU FF (fused dual-B)
  layernorm_kernel<<<dim3(2048), dim3(256), 0, stream>>>(x, ln3_g, ln3_b, lnb);
  {
    int nby = 2560 / 64, nwg = 64 * nby;
    gemm_geglu_kernel<<<dim3(nwg), dim3(256), 0, stream>>>(
        lnb, wT_gx, wT_gg, b_geglu, b_geglu + 2560, hb, 8192, 2560, 640,
        nby, nwg / 8, nwg % 8);
  }
  // ffout dual-writes fp32 x (with residual) AND bf16 lnb (A-operand for proj2)
  gemm(stream, hb, wT_ff, b_ffout, x, x, lnb, 8192, 640, 2560);

  // proj2 + input residual
  gemm(stream, lnb, wT_p2, b_proj2, inputs, (float*)d_out, nullptr, 8192, 640, 640);
}

// Round 29
// 513.346 us; speedup vs baseline: 1.0529x; 1.0529x over previous
//
#include <hip/hip_runtime.h>
#include <hip/hip_bf16.h>

// SpatialTransformer on MI355X. Round 29: T14 prefetch REVERTED (r28 regressed
// +7.6us: reg-prefetch adds VGPR + issue contention; TLP already hides staging
// latency). Attn restored to r27's proven form. NEW single change: GEGLU GEMM
// BM=256 via 8 waves x 512 threads (per-wave code byte-identical to r27's) —
// halves B-pair L2 re-sweeps per XCD chunk (B 6.5MB > 4MB L2 was the dominant
// refetch stream; FETCH 136MB). Bit-exact math.

#define HD 8
#define DHD 80
#define CCH 640
#define SQ 1024

using short8  = __attribute__((ext_vector_type(8))) short;
using floatx4 = __attribute__((ext_vector_type(4))) float;

__device__ __forceinline__ float bf2f(ushort u) {
  union { unsigned int i; float f; } v; v.i = ((unsigned int)u) << 16; return v.f;
}
__device__ __forceinline__ ushort f2bf(float f) {
  union { float f; unsigned int i; } v; v.f = f;
  unsigned int r = v.i + 0x7FFFu + ((v.i >> 16) & 1u);
  return (ushort)(r >> 16);
}
// 0.5*g*(1+tanh(z)) == g/(1+exp(-2z)), z = 0.79788456*g*(1+0.044715*g^2)
__device__ __forceinline__ float gelu_gate(float g) {
  float z = 0.7978845608f * g * (1.0f + 0.044715f * g * g);
  return g / (1.0f + __expf(-2.0f * z));
}

typedef const __attribute__((address_space(1))) void* gas_ptr;
typedef __attribute__((address_space(3))) void* las_ptr;
__device__ __forceinline__ void gload_lds16(const void* g, void* l) {
  __builtin_amdgcn_global_load_lds((gas_ptr)g, (las_ptr)l, 16, 0, 0);
}

// ---------------------------------------------------------------- GEMM
// C[M,N] = A[M,K]@BT[N,K]^T (+bias)(+res). BM=128, BN in {128,64}, BK=32,
// 4 waves 2x2. 2-buffer LDS, __syncthreads-delimited K-loop.
// outF and outB may BOTH be set (dual-write: fp32 + bf16 of the same value).
template<int BN>
__global__ __launch_bounds__(256) void gemm_bf16_kernel(
    const ushort* __restrict__ A, const ushort* __restrict__ BT,
    const float* __restrict__ bias, const float* __restrict__ res,
    float* __restrict__ outF, ushort* __restrict__ outB,
    int M, int N, int K, int nby, int q8, int r8)
{
  constexpr int NT = BN / 32;
  __shared__ ushort As[2][128][32];
  __shared__ ushort Bs[2][BN][32];
  const int tid  = threadIdx.x;
  const int lane = tid & 63;
  const int wave = tid >> 6;
  const int wm = (wave >> 1) * 64, wn = (wave & 1) * (BN / 2);

  // XCD-chunked bijective swizzle (bn-fastest logical order).
  const int orig = blockIdx.x;
  const int xcd = orig & 7, bix = orig >> 3;
  const int logical = (xcd < r8) ? xcd * (q8 + 1) + bix
                                 : r8 * (q8 + 1) + (xcd - r8) * q8 + bix;
  const int bm = (logical / nby) * 128;
  const int bn = (logical % nby) * BN;

  const int fr = lane & 15, fk = (lane >> 4) * 8;
  const bool full = (bm + 128 <= M);
  const int nt = K >> 5;

  floatx4 acc[4][NT];
  #pragma unroll
  for (int i = 0; i < 4; ++i)
    #pragma unroll
    for (int j = 0; j < NT; ++j) acc[i][j] = (floatx4){0.f, 0.f, 0.f, 0.f};

  const int lr = lane >> 2, lc = (lane & 3) * 8;
  const ushort* pA0 = A  + (size_t)(bm + wave * 16 + lr) * K + lc;
  const ushort* pA1 = pA0 + (size_t)64 * K;
  const ushort* pB0 = BT + (size_t)(bn + wave * 16 + lr) * K + lc;
  const ushort* pB1 = pB0 + (size_t)64 * K;
  const int r0 = tid >> 2, c0 = (tid & 3) * 8;

  auto stage = [&](int nb, int t) {
    const int kt = t * 32;
    if (full) {
      gload_lds16(pA0 + kt, &As[nb][wave * 16][0]);
      gload_lds16(pA1 + kt, &As[nb][wave * 16 + 64][0]);
      gload_lds16(pB0 + kt, &Bs[nb][wave * 16][0]);
      if (BN == 128) gload_lds16(pB1 + kt, &Bs[nb][wave * 16 + 64][0]);
    } else {
      #pragma unroll
      for (int it = 0; it < 2; ++it) {
        int r = r0 + it * 64;
        int gm = bm + r;
        uint4 va = make_uint4(0u, 0u, 0u, 0u);
        if (gm < M) va = *(const uint4*)(A + (size_t)gm * K + kt + c0);
        *(uint4*)(&As[nb][r][c0]) = va;
        if (r < BN) {
          int gn = bn + r;
          uint4 vb = make_uint4(0u, 0u, 0u, 0u);
          if (gn < N) vb = *(const uint4*)(BT + (size_t)gn * K + kt + c0);
          *(uint4*)(&Bs[nb][r][c0]) = vb;
        }
      }
    }
  };

  stage(0, 0);
  __syncthreads();
  int cur = 0;
  for (int t = 0; t < nt; ++t) {
    if (t + 1 < nt) stage(cur ^ 1, t + 1);
    short8 af[4], bfr[NT];
    #pragma unroll
    for (int mi = 0; mi < 4; ++mi) af[mi]  = *(const short8*)(&As[cur][wm + mi * 16 + fr][fk]);
    #pragma unroll
    for (int ni = 0; ni < NT; ++ni) bfr[ni] = *(const short8*)(&Bs[cur][wn + ni * 16 + fr][fk]);
    #pragma unroll
    for (int mi = 0; mi < 4; ++mi)
      #pragma unroll
      for (int ni = 0; ni < NT; ++ni)
        acc[mi][ni] = __builtin_amdgcn_mfma_f32_16x16x32_bf16(af[mi], bfr[ni], acc[mi][ni], 0, 0, 0);
    __syncthreads();
    cur ^= 1;
  }

  const int fq = (lane >> 4) * 4;
  #pragma unroll
  for (int mi = 0; mi < 4; ++mi)
    #pragma unroll
    for (int rr = 0; rr < 4; ++rr) {
      int gm = bm + wm + mi * 16 + fq + rr;
      if (gm >= M) continue;
      #pragma unroll
      for (int ni = 0; ni < NT; ++ni) {
        int col = bn + wn + ni * 16 + fr;
        float v = acc[mi][ni][rr];
        if (bias) v += bias[col];
        if (res) v += res[(size_t)gm * N + col];
        size_t o = (size_t)gm * N + col;
        if (outF) outF[o] = v;
        if (outB) outB[o] = f2bf(v);
      }
    }
}

// Fused GEGLU: out = (A@Bx^T + bx) * gelu(A@Bg^T + bg).
// Round 29: BM=256 via 8 waves (512 threads); per-wave compute identical to
// the r27 BM=128 form (acc[4][2] per op). Waves map 4 row-groups x 2 col-halves.
// A staged by all 8 waves (rows wave*16 and +128); Bx by waves 0-3, Bg by 4-7.
__global__ __launch_bounds__(512) void gemm_geglu_kernel(
    const ushort* __restrict__ A, const ushort* __restrict__ BTx,
    const ushort* __restrict__ BTg, const float* __restrict__ bx,
    const float* __restrict__ bg, ushort* __restrict__ outB,
    int M, int N, int K, int nby, int q8, int r8)
{
  __shared__ ushort As[2][256][32];   // 32 KB
  __shared__ ushort Bsx[2][64][32];   // 8 KB
  __shared__ ushort Bsg[2][64][32];   // 8 KB
  const int tid  = threadIdx.x;
  const int lane = tid & 63;
  const int wave = tid >> 6;          // 0..7
  const int wm = (wave >> 1) * 64, wn = (wave & 1) * 32;

  const int orig = blockIdx.x;
  const int xcd = orig & 7, bix = orig >> 3;
  const int logical = (xcd < r8) ? xcd * (q8 + 1) + bix
                                 : r8 * (q8 + 1) + (xcd - r8) * q8 + bix;
  const int bm = (logical / nby) * 256;
  const int bn = (logical % nby) * 64;

  const int fr = lane & 15, fk = (lane >> 4) * 8;
  const int nt = K >> 5;

  floatx4 accx[4][2], accg[4][2];
  #pragma unroll
  for (int i = 0; i < 4; ++i)
    #pragma unroll
    for (int j = 0; j < 2; ++j) {
      accx[i][j] = (floatx4){0.f, 0.f, 0.f, 0.f};
      accg[i][j] = (floatx4){0.f, 0.f, 0.f, 0.f};
    }

  const int lr = lane >> 2, lc = (lane & 3) * 8;
  const ushort* pA0 = A + (size_t)(bm + wave * 16 + lr) * K + lc;
  const ushort* pA1 = pA0 + (size_t)128 * K;
  const ushort* pB  = ((wave < 4) ? BTx : BTg)
                      + (size_t)(bn + (wave & 3) * 16 + lr) * K + lc;
  ushort* dstB0 = (wave < 4) ? &Bsx[0][(wave & 3) * 16][0] : &Bsg[0][(wave & 3) * 16][0];
  ushort* dstB1 = (wave < 4) ? &Bsx[1][(wave & 3) * 16][0] : &Bsg[1][(wave & 3) * 16][0];

  auto stage = [&](int nb, int t) {
    const int kt = t * 32;
    gload_lds16(pA0 + kt, &As[nb][wave * 16][0]);
    gload_lds16(pA1 + kt, &As[nb][wave * 16 + 128][0]);
    gload_lds16(pB + kt, nb ? dstB1 : dstB0);
  };

  stage(0, 0);
  __syncthreads();
  int cur = 0;
  for (int t = 0; t < nt; ++t) {
    if (t + 1 < nt) stage(cur ^ 1, t + 1);
    short8 af[4], bfx[2], bfg[2];
    #pragma unroll
    for (int mi = 0; mi < 4; ++mi) af[mi] = *(const short8*)(&As[cur][wm + mi * 16 + fr][fk]);
    #pragma unroll
    for (int ni = 0; ni < 2; ++ni) {
      bfx[ni] = *(const short8*)(&Bsx[cur][wn + ni * 16 + fr][fk]);
      bfg[ni] = *(const short8*)(&Bsg[cur][wn + ni * 16 + fr][fk]);
    }
    #pragma unroll
    for (int mi = 0; mi < 4; ++mi)
      #pragma unroll
      for (int ni = 0; ni < 2; ++ni) {
        accx[mi][ni] = __builtin_amdgcn_mfma_f32_16x16x32_bf16(af[mi], bfx[ni], accx[mi][ni], 0, 0, 0);
        accg[mi][ni] = __builtin_amdgcn_mfma_f32_16x16x32_bf16(af[mi], bfg[ni], accg[mi][ni], 0, 0, 0);
      }
    __syncthreads();
    cur ^= 1;
  }

  const int fq = (lane >> 4) * 4;
  #pragma unroll
  for (int mi = 0; mi < 4; ++mi)
    #pragma unroll
    for (int rr = 0; rr < 4; ++rr) {
      int gm = bm + wm + mi * 16 + fq + rr;
      #pragma unroll
      for (int ni = 0; ni < 2; ++ni) {
        int col = bn + wn + ni * 16 + fr;
        float xx = accx[mi][ni][rr] + bx[col];
        float g  = accg[mi][ni][rr] + bg[col];
        outB[(size_t)gm * N + col] = f2bf(xx * gelu_gate(g));
      }
    }
}

// ---------------------------------------------------------------- attention
// MFMA flash attention (r27 proven form): 8 waves x 16 q-rows = 128 q/block,
// KVB=64, grid 512, XCD-cluster swizzle, setprio, vectorized V staging.
// K staging covers ALL 80 columns (640 chunks, stride 512).
#define KVB 64

__global__ __launch_bounds__(512) void attn_mfma_kernel(
    const ushort* __restrict__ Qp, int rsq,
    const ushort* __restrict__ Kp, const ushort* __restrict__ Vp, int rskv,
    ushort* __restrict__ O, int Sq, int Sk)
{
  __shared__ ushort Ks[KVB][104];   // kv x d (d 0..95, 80..95 zeroed; +8 pad)
  __shared__ ushort Vt[80][88];     // d x kv
  __shared__ ushort Ps[8][16][88];  // per-wave P tile
  const int tid  = threadIdx.x;
  const int lane = tid & 63;
  const int w    = tid >> 6;        // 0..7
  const int l15  = lane & 15;
  const int lg   = lane >> 4;
  const int nqt  = Sq >> 7;         // q-tiles of 128
  // XCD-clustering swizzle: all nqt q-tiles of one bh share an XCD's L2.
  const int xcd8 = blockIdx.x & 7;
  const int sblk = blockIdx.x >> 3;
  const int qt   = sblk % nqt;
  const int bh   = (sblk / nqt) * 8 + xcd8;
  const int h    = bh & (HD - 1);
  const int b    = bh / HD;
  const int q0   = qt * 128 + w * 16;

  short8 qf[3];
  #pragma unroll
  for (int kc = 0; kc < 3; ++kc) {
    int d0 = kc * 32 + lg * 8;
    if (d0 < DHD)
      qf[kc] = *(const short8*)(Qp + (size_t)(b * Sq + q0 + l15) * rsq + h * DHD + d0);
    else
      qf[kc] = (short8){0, 0, 0, 0, 0, 0, 0, 0};
  }

  floatx4 oa[5];
  #pragma unroll
  for (int nt = 0; nt < 5; ++nt) oa[nt] = (floatx4){0.f, 0.f, 0.f, 0.f};
  float m[4], lsum[4];
  #pragma unroll
  for (int r = 0; r < 4; ++r) { m[r] = -1e30f; lsum[r] = 0.f; }

  for (int c = tid; c < 128; c += 512)
    *(uint4*)(&Ks[c >> 1][80 + (c & 1) * 8]) = make_uint4(0u, 0u, 0u, 0u);

  // V staging lane mapping: kv = tid&63, dblk0 = tid>>6 (0..7; +4,+8 ladder
  // covers d-blocks 0..9; overlapped blocks write identical data = benign)
  const int vkv    = tid & 63;
  const int vdblk0 = tid >> 6;

  for (int kt = 0; kt < Sk; kt += KVB) {
    __syncthreads();
    // stage K [64][80] FULLY: 640 x 16B chunks, stride 512
    for (int c = tid; c < 640; c += 512) {
      int row = c / 10, sub = c % 10;
      int kvg = kt + row;
      uint4 v = make_uint4(0u, 0u, 0u, 0u);
      if (kvg < Sk) v = *(const uint4*)(Kp + (size_t)(b * Sk + kvg) * rskv + h * DHD + sub * 8);
      *(uint4*)(&Ks[row][sub * 8]) = v;
    }
    // stage V transposed (always writes; zeros for masked kv)
    {
      int kvg = kt + vkv;
      const bool ok = (kvg < Sk);
      const ushort* src = Vp + (size_t)(b * Sk + kvg) * rskv + h * DHD + vdblk0 * 8;
      ushort* dst = &Vt[vdblk0 * 8][vkv];
      #pragma unroll
      for (int it = 0; it < 3; ++it) {
        if (vdblk0 + it * 4 < 10) {
          short8 v = (short8){0, 0, 0, 0, 0, 0, 0, 0};
          if (ok) v = *(const short8*)(src + it * 32);
          #pragma unroll
          for (int e = 0; e < 8; ++e)
            dst[(it * 32 + e) * 88] = (ushort)v[e];
        }
      }
    }
    __syncthreads();

    short8 kf[4][3];
    #pragma unroll
    for (int nt = 0; nt < 4; ++nt)
      #pragma unroll
      for (int kc = 0; kc < 3; ++kc)
        kf[nt][kc] = *(const short8*)(&Ks[nt * 16 + l15][kc * 32 + lg * 8]);
    floatx4 s[4];
    #pragma unroll
    for (int nt = 0; nt < 4; ++nt) s[nt] = (floatx4){0.f, 0.f, 0.f, 0.f};
    __builtin_amdgcn_s_setprio(1);
    #pragma unroll
    for (int nt = 0; nt < 4; ++nt)
      #pragma unroll
      for (int kc = 0; kc < 3; ++kc)
        s[nt] = __builtin_amdgcn_mfma_f32_16x16x32_bf16(qf[kc], kf[nt][kc], s[nt], 0, 0, 0);
    __builtin_amdgcn_s_setprio(0);

    const bool masked = (kt + KVB > Sk);
    #pragma unroll
    for (int r = 0; r < 4; ++r) {
      float sv[4];
      #pragma unroll
      for (int nt = 0; nt < 4; ++nt) {
        float t = s[nt][r];
        sv[nt] = (masked && (kt + nt * 16 + l15 >= Sk)) ? -1e30f : t;
      }
      float mx = fmaxf(fmaxf(sv[0], sv[1]), fmaxf(sv[2], sv[3]));
      mx = fmaxf(mx, __shfl_xor(mx, 1));
      mx = fmaxf(mx, __shfl_xor(mx, 2));
      mx = fmaxf(mx, __shfl_xor(mx, 4));
      mx = fmaxf(mx, __shfl_xor(mx, 8));
      float mn = fmaxf(m[r], mx);
      float al = __expf(m[r] - mn);
      m[r] = mn;
      float lt = 0.f;
      #pragma unroll
      for (int nt = 0; nt < 4; ++nt) {
        float p = __expf(sv[nt] - mn);
        lt += p;
        Ps[w][lg * 4 + r][nt * 16 + l15] = f2bf(p);
      }
      lt += __shfl_xor(lt, 1);
      lt += __shfl_xor(lt, 2);
      lt += __shfl_xor(lt, 4);
      lt += __shfl_xor(lt, 8);
      lsum[r] = lsum[r] * al + lt;
      #pragma unroll
      for (int nt = 0; nt < 5; ++nt) oa[nt][r] *= al;
    }

    short8 pf[2];
    #pragma unroll
    for (int kc2 = 0; kc2 < 2; ++kc2)
      pf[kc2] = *(const short8*)(&Ps[w][l15][kc2 * 32 + lg * 8]);
    __builtin_amdgcn_s_setprio(1);
    #pragma unroll
    for (int kc2 = 0; kc2 < 2; ++kc2)
      #pragma unroll
      for (int nt = 0; nt < 5; ++nt) {
        short8 vf = *(const short8*)(&Vt[nt * 16 + l15][kc2 * 32 + lg * 8]);
        oa[nt] = __builtin_amdgcn_mfma_f32_16x16x32_bf16(pf[kc2], vf, oa[nt], 0, 0, 0);
      }
    __builtin_amdgcn_s_setprio(0);
  }

  #pragma unroll
  for (int r = 0; r < 4; ++r) {
    float inv = 1.f / lsum[r];
    size_t row = (size_t)(b * Sq + q0 + lg * 4 + r) * CCH + h * DHD;
    #pragma unroll
    for (int nt = 0; nt < 5; ++nt)
      O[row + nt * 16 + l15] = f2bf(oa[nt][r] * inv);
  }
}

// ---------------------------------------------------------------- norms
__global__ __launch_bounds__(256) void layernorm_kernel(
    const float* __restrict__ X, const float* __restrict__ g,
    const float* __restrict__ bt, ushort* __restrict__ out)
{
  int row  = blockIdx.x * 4 + (threadIdx.x >> 6);
  int lane = threadIdx.x & 63;
  const float* xr = X + (size_t)row * CCH;
  float v[10];
  float s = 0.f, ss = 0.f;
  #pragma unroll
  for (int i = 0; i < 10; ++i) {
    float x = xr[lane + i * 64];
    v[i] = x; s += x; ss += x * x;
  }
  #pragma unroll
  for (int msk = 1; msk < 64; msk <<= 1) { s += __shfl_xor(s, msk); ss += __shfl_xor(ss, msk); }
  float mean = s * (1.f / 640.f);
  float var  = ss * (1.f / 640.f) - mean * mean;
  float rs   = rsqrtf(var + 1e-5f);
  ushort* orow = out + (size_t)row * CCH;
  #pragma unroll
  for (int i = 0; i < 10; ++i) {
    int c = lane + i * 64;
    orow[c] = f2bf((v[i] - mean) * rs * g[c] + bt[c]);
  }
}

__global__ __launch_bounds__(256) void groupnorm_kernel(
    const float* __restrict__ X, const float* __restrict__ gamma,
    const float* __restrict__ beta, ushort* __restrict__ out)
{
  int b = blockIdx.x >> 5;
  int g = blockIdx.x & 31;
  int tid = threadIdx.x;
  const float* base = X + (size_t)b * SQ * CCH + g * 20;
  float s = 0.f, ss = 0.f;
  for (int p = tid; p < SQ; p += 256) {
    const float* rp = base + (size_t)p * CCH;
    #pragma unroll
    for (int c = 0; c < 20; ++c) { float x = rp[c]; s += x; ss += x * x; }
  }
  #pragma unroll
  for (int msk = 1; msk < 64; msk <<= 1) { s += __shfl_xor(s, msk); ss += __shfl_xor(ss, msk); }
  __shared__ float red[2][4];
  int lane = tid & 63, wv = tid >> 6;
  if (lane == 0) { red[0][wv] = s; red[1][wv] = ss; }
  __syncthreads();
  s  = red[0][0] + red[0][1] + red[0][2] + red[0][3];
  ss = red[1][0] + red[1][1] + red[1][2] + red[1][3];
  float mean = s * (1.f / 20480.f);
  float var  = ss * (1.f / 20480.f) - mean * mean;
  float rstd = rsqrtf(var + 1e-5f);
  ushort* ob = out + (size_t)b * SQ * CCH + g * 20;
  for (int p = tid; p < SQ; p += 256) {
    const float* rp = base + (size_t)p * CCH;
    ushort* op = ob + (size_t)p * CCH;
    #pragma unroll
    for (int c = 0; c < 20; ++c)
      op[c] = f2bf((rp[c] - mean) * rstd * gamma[g * 20 + c] + beta[g * 20 + c]);
  }
}

// ---------------------------------------------------------------- prep
__global__ __launch_bounds__(256) void transpose_cast_kernel(
    const float* __restrict__ W, ushort* __restrict__ WT, int K, int ld,
    int coff, float scale)
{
  __shared__ float tile[32][33];
  const int tx = threadIdx.x, ty = threadIdx.y;
  const int k0 = blockIdx.x * 32, n0 = blockIdx.y * 32;
  #pragma unroll
  for (int i = 0; i < 4; ++i)
    tile[ty + i * 8][tx] = W[(size_t)(k0 + ty + i * 8) * ld + coff + n0 + tx];
  __syncthreads();
  #pragma unroll
  for (int i = 0; i < 4; ++i)
    WT[(size_t)(n0 + ty + i * 8) * K + k0 + tx] = f2bf(tile[tx][ty + i * 8] * scale);
}

__global__ void cast_kernel(const float* __restrict__ X, ushort* __restrict__ Y, int n)
{
  int i = (blockIdx.x * 256 + threadIdx.x) * 4;
  if (i < n) {
    float4 v = *(const float4*)(X + i);
    ushort4 o;
    o.x = f2bf(v.x); o.y = f2bf(v.y); o.z = f2bf(v.z); o.w = f2bf(v.w);
    *(ushort4*)(Y + i) = o;
  }
}

// ---------------------------------------------------------------- host
static inline void gemm(hipStream_t st, const ushort* A, const ushort* BT,
                        const float* bias, const float* res,
                        float* outF, ushort* outB, int M, int N, int K)
{
  int nbx = (M + 127) / 128;
  if (N % 128 == 0 && N > 640 && nbx * (N / 128) >= 512) {
    int nby = N / 128, nwg = nbx * nby;
    gemm_bf16_kernel<128><<<dim3(nwg), dim3(256), 0, st>>>(
        A, BT, bias, res, outF, outB, M, N, K, nby, nwg / 8, nwg % 8);
  } else {
    int nby = N / 64, nwg = nbx * nby;
    gemm_bf16_kernel<64><<<dim3(nwg), dim3(256), 0, st>>>(
        A, BT, bias, res, outF, outB, M, N, K, nby, nwg / 8, nwg % 8);
  }
}

extern "C" void kernel_launch(void* const* d_in, const int* in_sizes, int n_in,
                              void* d_out, int out_size, void* d_ws, size_t ws_size,
                              hipStream_t stream)
{
  const float* inputs  = (const float*)d_in[0];
  const float* context = (const float*)d_in[1];
  const float* gn_g    = (const float*)d_in[2];
  const float* gn_b    = (const float*)d_in[3];
  const float* w_proj1 = (const float*)d_in[4];
  const float* b_proj1 = (const float*)d_in[5];
  const float* ln1_g   = (const float*)d_in[6];
  const float* ln1_b   = (const float*)d_in[7];
  const float* wq1     = (const float*)d_in[8];
  const float* wk1     = (const float*)d_in[9];
  const float* wv1     = (const float*)d_in[10];
  const float* wo1     = (const float*)d_in[11];
  const float* bo1     = (const float*)d_in[12];
  const float* ln2_g   = (const float*)d_in[13];
  const float* ln2_b   = (const float*)d_in[14];
  const float* wq2     = (const float*)d_in[15];
  const float* wk2     = (const float*)d_in[16];
  const float* wv2     = (const float*)d_in[17];
  const float* wo2     = (const float*)d_in[18];
  const float* bo2     = (const float*)d_in[19];
  const float* ln3_g   = (const float*)d_in[20];
  const float* ln3_b   = (const float*)d_in[21];
  const float* w_geglu = (const float*)d_in[22];
  const float* b_geglu = (const float*)d_in[23];
  const float* w_ffout = (const float*)d_in[24];
  const float* b_ffout = (const float*)d_in[25];
  const float* w_proj2 = (const float*)d_in[26];
  const float* b_proj2 = (const float*)d_in[27];

  const float qscale = 0.11180339887498949f;  // 80^-0.5, folded into wq

  char* p = (char*)d_ws;
  auto alloc = [&](size_t bytes) -> char* {
    char* r = p; p += (bytes + 255) & ~(size_t)255; return r;
  };
  ushort* wT_p1   = (ushort*)alloc(640 * 640 * 2);
  ushort* wT_qkv1 = (ushort*)alloc((size_t)1920 * 640 * 2);
  ushort* wT_o1   = (ushort*)alloc(640 * 640 * 2);
  ushort* wT_q2   = (ushort*)alloc(640 * 640 * 2);
  ushort* wT_kv2  = (ushort*)alloc((size_t)1280 * 768 * 2);
  ushort* wT_o2   = (ushort*)alloc(640 * 640 * 2);
  ushort* wT_gx   = (ushort*)alloc((size_t)2560 * 640 * 2);
  ushort* wT_gg   = (ushort*)alloc((size_t)2560 * 640 * 2);
  ushort* wT_ff   = (ushort*)alloc((size_t)640 * 2560 * 2);
  ushort* wT_p2   = (ushort*)alloc(640 * 640 * 2);
  ushort* ctxb    = (ushort*)alloc((size_t)616 * 768 * 2);
  float*  x       = (float*)alloc((size_t)8192 * 640 * 4);
  ushort* lnb     = (ushort*)alloc((size_t)8192 * 640 * 2);
  ushort* R       = (ushort*)alloc((size_t)8192 * 2560 * 2);  // qkv / cross-q / hb
  ushort* kvb     = (ushort*)alloc((size_t)616 * 1280 * 2);
  ushort* qkvb = R;      // self q/k/v [8192][1920]
  ushort* qbx  = R;      // cross q [8192][640]
  ushort* hb   = R;      // GEGLU out [8192][2560]
  ushort* ab   = lnb;    // attn out aliases lnb

  auto T = [&](const float* W, ushort* WT, int K, int Nout, int ld, int coff, float sc) {
    dim3 g(K / 32, Nout / 32);
    transpose_cast_kernel<<<g, dim3(32, 8), 0, stream>>>(W, WT, K, ld, coff, sc);
  };
  T(w_proj1, wT_p1, 640, 640, 640, 0, 1.f);
  T(wq1, wT_qkv1,              640, 640, 640, 0, qscale);
  T(wk1, wT_qkv1 + 640 * 640,  640, 640, 640, 0, 1.f);
  T(wv1, wT_qkv1 + 1280 * 640, 640, 640, 640, 0, 1.f);
  T(wo1, wT_o1, 640, 640, 640, 0, 1.f);
  T(wq2, wT_q2, 640, 640, 640, 0, qscale);
  T(wk2, wT_kv2,             768, 640, 640, 0, 1.f);
  T(wv2, wT_kv2 + 640 * 768, 768, 640, 640, 0, 1.f);
  T(wo2, wT_o2, 640, 640, 640, 0, 1.f);
  T(w_geglu, wT_gx, 640, 2560, 5120, 0, 1.f);
  T(w_geglu, wT_gg, 640, 2560, 5120, 2560, 1.f);
  T(w_ffout, wT_ff, 2560, 640, 640, 0, 1.f);
  T(w_proj2, wT_p2, 640, 640, 640, 0, 1.f);
  cast_kernel<<<dim3((616 * 768 / 4 + 255) / 256), dim3(256), 0, stream>>>(context, ctxb, 616 * 768);

  // GN -> proj1
  groupnorm_kernel<<<dim3(256), dim3(256), 0, stream>>>(inputs, gn_g, gn_b, lnb);
  gemm(stream, lnb, wT_p1, b_proj1, nullptr, x, nullptr, 8192, 640, 640);

  // self-attention
  layernorm_kernel<<<dim3(2048), dim3(256), 0, stream>>>(x, ln1_g, ln1_b, lnb);
  gemm(stream, lnb, wT_qkv1, nullptr, nullptr, nullptr, qkvb, 8192, 1920, 640);
  attn_mfma_kernel<<<dim3(512), dim3(512), 0, stream>>>(qkvb, 1920, qkvb + 640, qkvb + 1280, 1920, ab, 1024, 1024);
  gemm(stream, ab, wT_o1, bo1, x, x, nullptr, 8192, 640, 640);

  // cross-attention
  layernorm_kernel<<<dim3(2048), dim3(256), 0, stream>>>(x, ln2_g, ln2_b, lnb);
  gemm(stream, lnb, wT_q2, nullptr, nullptr, nullptr, qbx, 8192, 640, 640);
  gemm(stream, ctxb, wT_kv2, nullptr, nullptr, nullptr, kvb, 616, 1280, 768);
  attn_mfma_kernel<<<dim3(512), dim3(512), 0, stream>>>(qbx, 640, kvb, kvb + 640, 1280, ab, 1024, 77);
  gemm(stream, ab, wT_o2, bo2, x, x, nullptr, 8192, 640, 640);

  // GEGLU FF (fused dual-B, BM=256 x 512 threads)
  layernorm_kernel<<<dim3(2048), dim3(256), 0, stream>>>(x, ln3_g, ln3_b, lnb);
  {
    int nby = 2560 / 64, nwg = (8192 / 256) * nby;   // 32 x 40 = 1280
    gemm_geglu_kernel<<<dim3(nwg), dim3(512), 0, stream>>>(
        lnb, wT_gx, wT_gg, b_geglu, b_geglu + 2560, hb, 8192, 2560, 640,
        nby, nwg / 8, nwg % 8);
  }
  // ffout dual-writes fp32 x (with residual) AND bf16 lnb (A-operand for proj2)
  gemm(stream, hb, wT_ff, b_ffout, x, x, lnb, 8192, 640, 2560);

  // proj2 + input residual
  gemm(stream, lnb, wT_p2, b_proj2, inputs, (float*)d_out, nullptr, 8192, 640, 640);
}

// Round 30
// 511.130 us; speedup vs baseline: 1.0575x; 1.0043x over previous
//
#include <hip/hip_runtime.h>
#include <hip/hip_bf16.h>

// SpatialTransformer on MI355X. Round 30: r29 (passed 513.3us; BM=256 GEGLU
// banked: FETCH 136->80MB) + grouped L2-aware block order inside the GEGLU
// XCD chunk: bn in groups of 8, bm-fastest within a group. Temporal working
// set = 4 A-panels (1.3MB) + 8 B-blocks (1.3MB) <= 4MB L2, so the B-pair is
// swept ONCE per XCD instead of once per bm-panel. Pure index remap (same
// block set) => bit-exact. Valid since nwg=1280 => r8=0, chunkSize=q8=160.

#define HD 8
#define DHD 80
#define CCH 640
#define SQ 1024

using short8  = __attribute__((ext_vector_type(8))) short;
using floatx4 = __attribute__((ext_vector_type(4))) float;

__device__ __forceinline__ float bf2f(ushort u) {
  union { unsigned int i; float f; } v; v.i = ((unsigned int)u) << 16; return v.f;
}
__device__ __forceinline__ ushort f2bf(float f) {
  union { float f; unsigned int i; } v; v.f = f;
  unsigned int r = v.i + 0x7FFFu + ((v.i >> 16) & 1u);
  return (ushort)(r >> 16);
}
// 0.5*g*(1+tanh(z)) == g/(1+exp(-2z)), z = 0.79788456*g*(1+0.044715*g^2)
__device__ __forceinline__ float gelu_gate(float g) {
  float z = 0.7978845608f * g * (1.0f + 0.044715f * g * g);
  return g / (1.0f + __expf(-2.0f * z));
}

typedef const __attribute__((address_space(1))) void* gas_ptr;
typedef __attribute__((address_space(3))) void* las_ptr;
__device__ __forceinline__ void gload_lds16(const void* g, void* l) {
  __builtin_amdgcn_global_load_lds((gas_ptr)g, (las_ptr)l, 16, 0, 0);
}

// ---------------------------------------------------------------- GEMM
// C[M,N] = A[M,K]@BT[N,K]^T (+bias)(+res). BM=128, BN in {128,64}, BK=32,
// 4 waves 2x2. 2-buffer LDS, __syncthreads-delimited K-loop.
// outF and outB may BOTH be set (dual-write: fp32 + bf16 of the same value).
template<int BN>
__global__ __launch_bounds__(256) void gemm_bf16_kernel(
    const ushort* __restrict__ A, const ushort* __restrict__ BT,
    const float* __restrict__ bias, const float* __restrict__ res,
    float* __restrict__ outF, ushort* __restrict__ outB,
    int M, int N, int K, int nby, int q8, int r8)
{
  constexpr int NT = BN / 32;
  __shared__ ushort As[2][128][32];
  __shared__ ushort Bs[2][BN][32];
  const int tid  = threadIdx.x;
  const int lane = tid & 63;
  const int wave = tid >> 6;
  const int wm = (wave >> 1) * 64, wn = (wave & 1) * (BN / 2);

  // XCD-chunked bijective swizzle (bn-fastest logical order).
  const int orig = blockIdx.x;
  const int xcd = orig & 7, bix = orig >> 3;
  const int logical = (xcd < r8) ? xcd * (q8 + 1) + bix
                                 : r8 * (q8 + 1) + (xcd - r8) * q8 + bix;
  const int bm = (logical / nby) * 128;
  const int bn = (logical % nby) * BN;

  const int fr = lane & 15, fk = (lane >> 4) * 8;
  const bool full = (bm + 128 <= M);
  const int nt = K >> 5;

  floatx4 acc[4][NT];
  #pragma unroll
  for (int i = 0; i < 4; ++i)
    #pragma unroll
    for (int j = 0; j < NT; ++j) acc[i][j] = (floatx4){0.f, 0.f, 0.f, 0.f};

  const int lr = lane >> 2, lc = (lane & 3) * 8;
  const ushort* pA0 = A  + (size_t)(bm + wave * 16 + lr) * K + lc;
  const ushort* pA1 = pA0 + (size_t)64 * K;
  const ushort* pB0 = BT + (size_t)(bn + wave * 16 + lr) * K + lc;
  const ushort* pB1 = pB0 + (size_t)64 * K;
  const int r0 = tid >> 2, c0 = (tid & 3) * 8;

  auto stage = [&](int nb, int t) {
    const int kt = t * 32;
    if (full) {
      gload_lds16(pA0 + kt, &As[nb][wave * 16][0]);
      gload_lds16(pA1 + kt, &As[nb][wave * 16 + 64][0]);
      gload_lds16(pB0 + kt, &Bs[nb][wave * 16][0]);
      if (BN == 128) gload_lds16(pB1 + kt, &Bs[nb][wave * 16 + 64][0]);
    } else {
      #pragma unroll
      for (int it = 0; it < 2; ++it) {
        int r = r0 + it * 64;
        int gm = bm + r;
        uint4 va = make_uint4(0u, 0u, 0u, 0u);
        if (gm < M) va = *(const uint4*)(A + (size_t)gm * K + kt + c0);
        *(uint4*)(&As[nb][r][c0]) = va;
        if (r < BN) {
          int gn = bn + r;
          uint4 vb = make_uint4(0u, 0u, 0u, 0u);
          if (gn < N) vb = *(const uint4*)(BT + (size_t)gn * K + kt + c0);
          *(uint4*)(&Bs[nb][r][c0]) = vb;
        }
      }
    }
  };

  stage(0, 0);
  __syncthreads();
  int cur = 0;
  for (int t = 0; t < nt; ++t) {
    if (t + 1 < nt) stage(cur ^ 1, t + 1);
    short8 af[4], bfr[NT];
    #pragma unroll
    for (int mi = 0; mi < 4; ++mi) af[mi]  = *(const short8*)(&As[cur][wm + mi * 16 + fr][fk]);
    #pragma unroll
    for (int ni = 0; ni < NT; ++ni) bfr[ni] = *(const short8*)(&Bs[cur][wn + ni * 16 + fr][fk]);
    #pragma unroll
    for (int mi = 0; mi < 4; ++mi)
      #pragma unroll
      for (int ni = 0; ni < NT; ++ni)
        acc[mi][ni] = __builtin_amdgcn_mfma_f32_16x16x32_bf16(af[mi], bfr[ni], acc[mi][ni], 0, 0, 0);
    __syncthreads();
    cur ^= 1;
  }

  const int fq = (lane >> 4) * 4;
  #pragma unroll
  for (int mi = 0; mi < 4; ++mi)
    #pragma unroll
    for (int rr = 0; rr < 4; ++rr) {
      int gm = bm + wm + mi * 16 + fq + rr;
      if (gm >= M) continue;
      #pragma unroll
      for (int ni = 0; ni < NT; ++ni) {
        int col = bn + wn + ni * 16 + fr;
        float v = acc[mi][ni][rr];
        if (bias) v += bias[col];
        if (res) v += res[(size_t)gm * N + col];
        size_t o = (size_t)gm * N + col;
        if (outF) outF[o] = v;
        if (outB) outB[o] = f2bf(v);
      }
    }
}

// Fused GEGLU: out = (A@Bx^T + bx) * gelu(A@Bg^T + bg).
// BM=256 via 8 waves (512 threads); per-wave compute identical to the BM=128
// form (acc[4][2] per op). Round 30: grouped block order within the XCD chunk
// (bn groups of 8, bm-fastest inside) for L2 residency of A-panels + B-group.
__global__ __launch_bounds__(512) void gemm_geglu_kernel(
    const ushort* __restrict__ A, const ushort* __restrict__ BTx,
    const ushort* __restrict__ BTg, const float* __restrict__ bx,
    const float* __restrict__ bg, ushort* __restrict__ outB,
    int M, int N, int K, int nby, int q8, int r8)
{
  __shared__ ushort As[2][256][32];   // 32 KB
  __shared__ ushort Bsx[2][64][32];   // 8 KB
  __shared__ ushort Bsg[2][64][32];   // 8 KB
  const int tid  = threadIdx.x;
  const int lane = tid & 63;
  const int wave = tid >> 6;          // 0..7
  const int wm = (wave >> 1) * 64, wn = (wave & 1) * 32;

  const int orig = blockIdx.x;
  const int xcd = orig & 7, bix = orig >> 3;
  const int logical = (xcd < r8) ? xcd * (q8 + 1) + bix
                                 : r8 * (q8 + 1) + (xcd - r8) * q8 + bix;
  // Grouped decode within the XCD chunk (requires r8==0; chunkSize=q8=160,
  // 4 bm-panels x 40 bn per chunk; G=8 bn per group, bm-fastest in-group):
  // sub = i & 31 -> (bm within 4, bn within G); grp = i >> 5 -> bn group.
  const int chunk = logical / q8;
  const int i     = logical - chunk * q8;
  const int sub   = i & 31;
  const int grp   = i >> 5;
  const int bm = (chunk * 4 + (sub & 3)) * 256;
  const int bn = (grp * 8 + (sub >> 2)) * 64;

  const int fr = lane & 15, fk = (lane >> 4) * 8;
  const int nt = K >> 5;

  floatx4 accx[4][2], accg[4][2];
  #pragma unroll
  for (int i2 = 0; i2 < 4; ++i2)
    #pragma unroll
    for (int j = 0; j < 2; ++j) {
      accx[i2][j] = (floatx4){0.f, 0.f, 0.f, 0.f};
      accg[i2][j] = (floatx4){0.f, 0.f, 0.f, 0.f};
    }

  const int lr = lane >> 2, lc = (lane & 3) * 8;
  const ushort* pA0 = A + (size_t)(bm + wave * 16 + lr) * K + lc;
  const ushort* pA1 = pA0 + (size_t)128 * K;
  const ushort* pB  = ((wave < 4) ? BTx : BTg)
                      + (size_t)(bn + (wave & 3) * 16 + lr) * K + lc;
  ushort* dstB0 = (wave < 4) ? &Bsx[0][(wave & 3) * 16][0] : &Bsg[0][(wave & 3) * 16][0];
  ushort* dstB1 = (wave < 4) ? &Bsx[1][(wave & 3) * 16][0] : &Bsg[1][(wave & 3) * 16][0];

  auto stage = [&](int nb, int t) {
    const int kt = t * 32;
    gload_lds16(pA0 + kt, &As[nb][wave * 16][0]);
    gload_lds16(pA1 + kt, &As[nb][wave * 16 + 128][0]);
    gload_lds16(pB + kt, nb ? dstB1 : dstB0);
  };

  stage(0, 0);
  __syncthreads();
  int cur = 0;
  for (int t = 0; t < nt; ++t) {
    if (t + 1 < nt) stage(cur ^ 1, t + 1);
    short8 af[4], bfx[2], bfg[2];
    #pragma unroll
    for (int mi = 0; mi < 4; ++mi) af[mi] = *(const short8*)(&As[cur][wm + mi * 16 + fr][fk]);
    #pragma unroll
    for (int ni = 0; ni < 2; ++ni) {
      bfx[ni] = *(const short8*)(&Bsx[cur][wn + ni * 16 + fr][fk]);
      bfg[ni] = *(const short8*)(&Bsg[cur][wn + ni * 16 + fr][fk]);
    }
    #pragma unroll
    for (int mi = 0; mi < 4; ++mi)
      #pragma unroll
      for (int ni = 0; ni < 2; ++ni) {
        accx[mi][ni] = __builtin_amdgcn_mfma_f32_16x16x32_bf16(af[mi], bfx[ni], accx[mi][ni], 0, 0, 0);
        accg[mi][ni] = __builtin_amdgcn_mfma_f32_16x16x32_bf16(af[mi], bfg[ni], accg[mi][ni], 0, 0, 0);
      }
    __syncthreads();
    cur ^= 1;
  }

  const int fq = (lane >> 4) * 4;
  #pragma unroll
  for (int mi = 0; mi < 4; ++mi)
    #pragma unroll
    for (int rr = 0; rr < 4; ++rr) {
      int gm = bm + wm + mi * 16 + fq + rr;
      #pragma unroll
      for (int ni = 0; ni < 2; ++ni) {
        int col = bn + wn + ni * 16 + fr;
        float xx = accx[mi][ni][rr] + bx[col];
        float g  = accg[mi][ni][rr] + bg[col];
        outB[(size_t)gm * N + col] = f2bf(xx * gelu_gate(g));
      }
    }
}

// ---------------------------------------------------------------- attention
// MFMA flash attention (r27 proven form): 8 waves x 16 q-rows = 128 q/block,
// KVB=64, grid 512, XCD-cluster swizzle, setprio, vectorized V staging.
// K staging covers ALL 80 columns (640 chunks, stride 512).
#define KVB 64

__global__ __launch_bounds__(512) void attn_mfma_kernel(
    const ushort* __restrict__ Qp, int rsq,
    const ushort* __restrict__ Kp, const ushort* __restrict__ Vp, int rskv,
    ushort* __restrict__ O, int Sq, int Sk)
{
  __shared__ ushort Ks[KVB][104];   // kv x d (d 0..95, 80..95 zeroed; +8 pad)
  __shared__ ushort Vt[80][88];     // d x kv
  __shared__ ushort Ps[8][16][88];  // per-wave P tile
  const int tid  = threadIdx.x;
  const int lane = tid & 63;
  const int w    = tid >> 6;        // 0..7
  const int l15  = lane & 15;
  const int lg   = lane >> 4;
  const int nqt  = Sq >> 7;         // q-tiles of 128
  // XCD-clustering swizzle: all nqt q-tiles of one bh share an XCD's L2.
  const int xcd8 = blockIdx.x & 7;
  const int sblk = blockIdx.x >> 3;
  const int qt   = sblk % nqt;
  const int bh   = (sblk / nqt) * 8 + xcd8;
  const int h    = bh & (HD - 1);
  const int b    = bh / HD;
  const int q0   = qt * 128 + w * 16;

  short8 qf[3];
  #pragma unroll
  for (int kc = 0; kc < 3; ++kc) {
    int d0 = kc * 32 + lg * 8;
    if (d0 < DHD)
      qf[kc] = *(const short8*)(Qp + (size_t)(b * Sq + q0 + l15) * rsq + h * DHD + d0);
    else
      qf[kc] = (short8){0, 0, 0, 0, 0, 0, 0, 0};
  }

  floatx4 oa[5];
  #pragma unroll
  for (int nt = 0; nt < 5; ++nt) oa[nt] = (floatx4){0.f, 0.f, 0.f, 0.f};
  float m[4], lsum[4];
  #pragma unroll
  for (int r = 0; r < 4; ++r) { m[r] = -1e30f; lsum[r] = 0.f; }

  for (int c = tid; c < 128; c += 512)
    *(uint4*)(&Ks[c >> 1][80 + (c & 1) * 8]) = make_uint4(0u, 0u, 0u, 0u);

  // V staging lane mapping: kv = tid&63, dblk0 = tid>>6 (0..7; +4,+8 ladder
  // covers d-blocks 0..9; overlapped blocks write identical data = benign)
  const int vkv    = tid & 63;
  const int vdblk0 = tid >> 6;

  for (int kt = 0; kt < Sk; kt += KVB) {
    __syncthreads();
    // stage K [64][80] FULLY: 640 x 16B chunks, stride 512
    for (int c = tid; c < 640; c += 512) {
      int row = c / 10, sub = c % 10;
      int kvg = kt + row;
      uint4 v = make_uint4(0u, 0u, 0u, 0u);
      if (kvg < Sk) v = *(const uint4*)(Kp + (size_t)(b * Sk + kvg) * rskv + h * DHD + sub * 8);
      *(uint4*)(&Ks[row][sub * 8]) = v;
    }
    // stage V transposed (always writes; zeros for masked kv)
    {
      int kvg = kt + vkv;
      const bool ok = (kvg < Sk);
      const ushort* src = Vp + (size_t)(b * Sk + kvg) * rskv + h * DHD + vdblk0 * 8;
      ushort* dst = &Vt[vdblk0 * 8][vkv];
      #pragma unroll
      for (int it = 0; it < 3; ++it) {
        if (vdblk0 + it * 4 < 10) {
          short8 v = (short8){0, 0, 0, 0, 0, 0, 0, 0};
          if (ok) v = *(const short8*)(src + it * 32);
          #pragma unroll
          for (int e = 0; e < 8; ++e)
            dst[(it * 32 + e) * 88] = (ushort)v[e];
        }
      }
    }
    __syncthreads();

    short8 kf[4][3];
    #pragma unroll
    for (int nt = 0; nt < 4; ++nt)
      #pragma unroll
      for (int kc = 0; kc < 3; ++kc)
        kf[nt][kc] = *(const short8*)(&Ks[nt * 16 + l15][kc * 32 + lg * 8]);
    floatx4 s[4];
    #pragma unroll
    for (int nt = 0; nt < 4; ++nt) s[nt] = (floatx4){0.f, 0.f, 0.f, 0.f};
    __builtin_amdgcn_s_setprio(1);
    #pragma unroll
    for (int nt = 0; nt < 4; ++nt)
      #pragma unroll
      for (int kc = 0; kc < 3; ++kc)
        s[nt] = __builtin_amdgcn_mfma_f32_16x16x32_bf16(qf[kc], kf[nt][kc], s[nt], 0, 0, 0);
    __builtin_amdgcn_s_setprio(0);

    const bool masked = (kt + KVB > Sk);
    #pragma unroll
    for (int r = 0; r < 4; ++r) {
      float sv[4];
      #pragma unroll
      for (int nt = 0; nt < 4; ++nt) {
        float t = s[nt][r];
        sv[nt] = (masked && (kt + nt * 16 + l15 >= Sk)) ? -1e30f : t;
      }
      float mx = fmaxf(fmaxf(sv[0], sv[1]), fmaxf(sv[2], sv[3]));
      mx = fmaxf(mx, __shfl_xor(mx, 1));
      mx = fmaxf(mx, __shfl_xor(mx, 2));
      mx = fmaxf(mx, __shfl_xor(mx, 4));
      mx = fmaxf(mx, __shfl_xor(mx, 8));
      float mn = fmaxf(m[r], mx);
      float al = __expf(m[r] - mn);
      m[r] = mn;
      float lt = 0.f;
      #pragma unroll
      for (int nt = 0; nt < 4; ++nt) {
        float p = __expf(sv[nt] - mn);
        lt += p;
        Ps[w][lg * 4 + r][nt * 16 + l15] = f2bf(p);
      }
      lt += __shfl_xor(lt, 1);
      lt += __shfl_xor(lt, 2);
      lt += __shfl_xor(lt, 4);
      lt += __shfl_xor(lt, 8);
      lsum[r] = lsum[r] * al + lt;
      #pragma unroll
      for (int nt = 0; nt < 5; ++nt) oa[nt][r] *= al;
    }

    short8 pf[2];
    #pragma unroll
    for (int kc2 = 0; kc2 < 2; ++kc2)
      pf[kc2] = *(const short8*)(&Ps[w][l15][kc2 * 32 + lg * 8]);
    __builtin_amdgcn_s_setprio(1);
    #pragma unroll
    for (int kc2 = 0; kc2 < 2; ++kc2)
      #pragma unroll
      for (int nt = 0; nt < 5; ++nt) {
        short8 vf = *(const short8*)(&Vt[nt * 16 + l15][kc2 * 32 + lg * 8]);
        oa[nt] = __builtin_amdgcn_mfma_f32_16x16x32_bf16(pf[kc2], vf, oa[nt], 0, 0, 0);
      }
    __builtin_amdgcn_s_setprio(0);
  }

  #pragma unroll
  for (int r = 0; r < 4; ++r) {
    float inv = 1.f / lsum[r];
    size_t row = (size_t)(b * Sq + q0 + lg * 4 + r) * CCH + h * DHD;
    #pragma unroll
    for (int nt = 0; nt < 5; ++nt)
      O[row + nt * 16 + l15] = f2bf(oa[nt][r] * inv);
  }
}

// ---------------------------------------------------------------- norms
__global__ __launch_bounds__(256) void layernorm_kernel(
    const float* __restrict__ X, const float* __restrict__ g,
    const float* __restrict__ bt, ushort* __restrict__ out)
{
  int row  = blockIdx.x * 4 + (threadIdx.x >> 6);
  int lane = threadIdx.x & 63;
  const float* xr = X + (size_t)row * CCH;
  float v[10];
  float s = 0.f, ss = 0.f;
  #pragma unroll
  for (int i = 0; i < 10; ++i) {
    float x = xr[lane + i * 64];
    v[i] = x; s += x; ss += x * x;
  }
  #pragma unroll
  for (int msk = 1; msk < 64; msk <<= 1) { s += __shfl_xor(s, msk); ss += __shfl_xor(ss, msk); }
  float mean = s * (1.f / 640.f);
  float var  = ss * (1.f / 640.f) - mean * mean;
  float rs   = rsqrtf(var + 1e-5f);
  ushort* orow = out + (size_t)row * CCH;
  #pragma unroll
  for (int i = 0; i < 10; ++i) {
    int c = lane + i * 64;
    orow[c] = f2bf((v[i] - mean) * rs * g[c] + bt[c]);
  }
}

__global__ __launch_bounds__(256) void groupnorm_kernel(
    const float* __restrict__ X, const float* __restrict__ gamma,
    const float* __restrict__ beta, ushort* __restrict__ out)
{
  int b = blockIdx.x >> 5;
  int g = blockIdx.x & 31;
  int tid = threadIdx.x;
  const float* base = X + (size_t)b * SQ * CCH + g * 20;
  float s = 0.f, ss = 0.f;
  for (int p = tid; p < SQ; p += 256) {
    const float* rp = base + (size_t)p * CCH;
    #pragma unroll
    for (int c = 0; c < 20; ++c) { float x = rp[c]; s += x; ss += x * x; }
  }
  #pragma unroll
  for (int msk = 1; msk < 64; msk <<= 1) { s += __shfl_xor(s, msk); ss += __shfl_xor(ss, msk); }
  __shared__ float red[2][4];
  int lane = tid & 63, wv = tid >> 6;
  if (lane == 0) { red[0][wv] = s; red[1][wv] = ss; }
  __syncthreads();
  s  = red[0][0] + red[0][1] + red[0][2] + red[0][3];
  ss = red[1][0] + red[1][1] + red[1][2] + red[1][3];
  float mean = s * (1.f / 20480.f);
  float var  = ss * (1.f / 20480.f) - mean * mean;
  float rstd = rsqrtf(var + 1e-5f);
  ushort* ob = out + (size_t)b * SQ * CCH + g * 20;
  for (int p = tid; p < SQ; p += 256) {
    const float* rp = base + (size_t)p * CCH;
    ushort* op = ob + (size_t)p * CCH;
    #pragma unroll
    for (int c = 0; c < 20; ++c)
      op[c] = f2bf((rp[c] - mean) * rstd * gamma[g * 20 + c] + beta[g * 20 + c]);
  }
}

// ---------------------------------------------------------------- prep
__global__ __launch_bounds__(256) void transpose_cast_kernel(
    const float* __restrict__ W, ushort* __restrict__ WT, int K, int ld,
    int coff, float scale)
{
  __shared__ float tile[32][33];
  const int tx = threadIdx.x, ty = threadIdx.y;
  const int k0 = blockIdx.x * 32, n0 = blockIdx.y * 32;
  #pragma unroll
  for (int i = 0; i < 4; ++i)
    tile[ty + i * 8][tx] = W[(size_t)(k0 + ty + i * 8) * ld + coff + n0 + tx];
  __syncthreads();
  #pragma unroll
  for (int i = 0; i < 4; ++i)
    WT[(size_t)(n0 + ty + i * 8) * K + k0 + tx] = f2bf(tile[tx][ty + i * 8] * scale);
}

__global__ void cast_kernel(const float* __restrict__ X, ushort* __restrict__ Y, int n)
{
  int i = (blockIdx.x * 256 + threadIdx.x) * 4;
  if (i < n) {
    float4 v = *(const float4*)(X + i);
    ushort4 o;
    o.x = f2bf(v.x); o.y = f2bf(v.y); o.z = f2bf(v.z); o.w = f2bf(v.w);
    *(ushort4*)(Y + i) = o;
  }
}

// ---------------------------------------------------------------- host
static inline void gemm(hipStream_t st, const ushort* A, const ushort* BT,
                        const float* bias, const float* res,
                        float* outF, ushort* outB, int M, int N, int K)
{
  int nbx = (M + 127) / 128;
  if (N % 128 == 0 && N > 640 && nbx * (N / 128) >= 512) {
    int nby = N / 128, nwg = nbx * nby;
    gemm_bf16_kernel<128><<<dim3(nwg), dim3(256), 0, st>>>(
        A, BT, bias, res, outF, outB, M, N, K, nby, nwg / 8, nwg % 8);
  } else {
    int nby = N / 64, nwg = nbx * nby;
    gemm_bf16_kernel<64><<<dim3(nwg), dim3(256), 0, st>>>(
        A, BT, bias, res, outF, outB, M, N, K, nby, nwg / 8, nwg % 8);
  }
}

extern "C" void kernel_launch(void* const* d_in, const int* in_sizes, int n_in,
                              void* d_out, int out_size, void* d_ws, size_t ws_size,
                              hipStream_t stream)
{
  const float* inputs  = (const float*)d_in[0];
  const float* context = (const float*)d_in[1];
  const float* gn_g    = (const float*)d_in[2];
  const float* gn_b    = (const float*)d_in[3];
  const float* w_proj1 = (const float*)d_in[4];
  const float* b_proj1 = (const float*)d_in[5];
  const float* ln1_g   = (const float*)d_in[6];
  const float* ln1_b   = (const float*)d_in[7];
  const float* wq1     = (const float*)d_in[8];
  const float* wk1     = (const float*)d_in[9];
  const float* wv1     = (const float*)d_in[10];
  const float* wo1     = (const float*)d_in[11];
  const float* bo1     = (const float*)d_in[12];
  const float* ln2_g   = (const float*)d_in[13];
  const float* ln2_b   = (const float*)d_in[14];
  const float* wq2     = (const float*)d_in[15];
  const float* wk2     = (const float*)d_in[16];
  const float* wv2     = (const float*)d_in[17];
  const float* wo2     = (const float*)d_in[18];
  const float* bo2     = (const float*)d_in[19];
  const float* ln3_g   = (const float*)d_in[20];
  const float* ln3_b   = (const float*)d_in[21];
  const float* w_geglu = (const float*)d_in[22];
  const float* b_geglu = (const float*)d_in[23];
  const float* w_ffout = (const float*)d_in[24];
  const float* b_ffout = (const float*)d_in[25];
  const float* w_proj2 = (const float*)d_in[26];
  const float* b_proj2 = (const float*)d_in[27];

  const float qscale = 0.11180339887498949f;  // 80^-0.5, folded into wq

  char* p = (char*)d_ws;
  auto alloc = [&](size_t bytes) -> char* {
    char* r = p; p += (bytes + 255) & ~(size_t)255; return r;
  };
  ushort* wT_p1   = (ushort*)alloc(640 * 640 * 2);
  ushort* wT_qkv1 = (ushort*)alloc((size_t)1920 * 640 * 2);
  ushort* wT_o1   = (ushort*)alloc(640 * 640 * 2);
  ushort* wT_q2   = (ushort*)alloc(640 * 640 * 2);
  ushort* wT_kv2  = (ushort*)alloc((size_t)1280 * 768 * 2);
  ushort* wT_o2   = (ushort*)alloc(640 * 640 * 2);
  ushort* wT_gx   = (ushort*)alloc((size_t)2560 * 640 * 2);
  ushort* wT_gg   = (ushort*)alloc((size_t)2560 * 640 * 2);
  ushort* wT_ff   = (ushort*)alloc((size_t)640 * 2560 * 2);
  ushort* wT_p2   = (ushort*)alloc(640 * 640 * 2);
  ushort* ctxb    = (ushort*)alloc((size_t)616 * 768 * 2);
  float*  x       = (float*)alloc((size_t)8192 * 640 * 4);
  ushort* lnb     = (ushort*)alloc((size_t)8192 * 640 * 2);
  ushort* R       = (ushort*)alloc((size_t)8192 * 2560 * 2);  // qkv / cross-q / hb
  ushort* kvb     = (ushort*)alloc((size_t)616 * 1280 * 2);
  ushort* qkvb = R;      // self q/k/v [8192][1920]
  ushort* qbx  = R;      // cross q [8192][640]
  ushort* hb   = R;      // GEGLU out [8192][2560]
  ushort* ab   = lnb;    // attn out aliases lnb

  auto T = [&](const float* W, ushort* WT, int K, int Nout, int ld, int coff, float sc) {
    dim3 g(K / 32, Nout / 32);
    transpose_cast_kernel<<<g, dim3(32, 8), 0, stream>>>(W, WT, K, ld, coff, sc);
  };
  T(w_proj1, wT_p1, 640, 640, 640, 0, 1.f);
  T(wq1, wT_qkv1,              640, 640, 640, 0, qscale);
  T(wk1, wT_qkv1 + 640 * 640,  640, 640, 640, 0, 1.f);
  T(wv1, wT_qkv1 + 1280 * 640, 640, 640, 640, 0, 1.f);
  T(wo1, wT_o1, 640, 640, 640, 0, 1.f);
  T(wq2, wT_q2, 640, 640, 640, 0, qscale);
  T(wk2, wT_kv2,             768, 640, 640, 0, 1.f);
  T(wv2, wT_kv2 + 640 * 768, 768, 640, 640, 0, 1.f);
  T(wo2, wT_o2, 640, 640, 640, 0, 1.f);
  T(w_geglu, wT_gx, 640, 2560, 5120, 0, 1.f);
  T(w_geglu, wT_gg, 640, 2560, 5120, 2560, 1.f);
  T(w_ffout, wT_ff, 2560, 640, 640, 0, 1.f);
  T(w_proj2, wT_p2, 640, 640, 640, 0, 1.f);
  cast_kernel<<<dim3((616 * 768 / 4 + 255) / 256), dim3(256), 0, stream>>>(context, ctxb, 616 * 768);

  // GN -> proj1
  groupnorm_kernel<<<dim3(256), dim3(256), 0, stream>>>(inputs, gn_g, gn_b, lnb);
  gemm(stream, lnb, wT_p1, b_proj1, nullptr, x, nullptr, 8192, 640, 640);

  // self-attention
  layernorm_kernel<<<dim3(2048), dim3(256), 0, stream>>>(x, ln1_g, ln1_b, lnb);
  gemm(stream, lnb, wT_qkv1, nullptr, nullptr, nullptr, qkvb, 8192, 1920, 640);
  attn_mfma_kernel<<<dim3(512), dim3(512), 0, stream>>>(qkvb, 1920, qkvb + 640, qkvb + 1280, 1920, ab, 1024, 1024);
  gemm(stream, ab, wT_o1, bo1, x, x, nullptr, 8192, 640, 640);

  // cross-attention
  layernorm_kernel<<<dim3(2048), dim3(256), 0, stream>>>(x, ln2_g, ln2_b, lnb);
  gemm(stream, lnb, wT_q2, nullptr, nullptr, nullptr, qbx, 8192, 640, 640);
  gemm(stream, ctxb, wT_kv2, nullptr, nullptr, nullptr, kvb, 616, 1280, 768);
  attn_mfma_kernel<<<dim3(512), dim3(512), 0, stream>>>(qbx, 640, kvb, kvb + 640, 1280, ab, 1024, 77);
  gemm(stream, ab, wT_o2, bo2, x, x, nullptr, 8192, 640, 640);

  // GEGLU FF (fused dual-B, BM=256 x 512 threads, grouped block order)
  layernorm_kernel<<<dim3(2048), dim3(256), 0, stream>>>(x, ln3_g, ln3_b, lnb);
  {
    int nby = 2560 / 64, nwg = (8192 / 256) * nby;   // 32 x 40 = 1280
    gemm_geglu_kernel<<<dim3(nwg), dim3(512), 0, stream>>>(
        lnb, wT_gx, wT_gg, b_geglu, b_geglu + 2560, hb, 8192, 2560, 640,
        nby, nwg / 8, nwg % 8);
  }
  // ffout dual-writes fp32 x (with residual) AND bf16 lnb (A-operand for proj2)
  gemm(stream, hb, wT_ff, b_ffout, x, x, lnb, 8192, 640, 2560);

  // proj2 + input residual
  gemm(stream, lnb, wT_p2, b_proj2, inputs, (float*)d_out, nullptr, 8192, 640, 640);
}